// Round 3
// baseline (991.917 us; speedup 1.0000x reference)
//
#include <hip/hip_runtime.h>
#include <math.h>

// Problem constants (from reference)
#define N_    128
#define T_    1000
#define NS_   10
#define NO_   10
#define HID_  64
#define DENSE_ 32

typedef float v2f __attribute__((ext_vector_type(2)));
typedef float v4f __attribute__((ext_vector_type(4)));

// packed 2-wide f32 fma: acc = a*b + acc  (V_PK_FMA_F32, VOP3P)
#define PKFMA(acc, a, b) \
    asm("v_pk_fma_f32 %0, %1, %2, %0" : "+v"(acc) : "v"(a), "v"(b))

__device__ __forceinline__ float fast_sigmoid(float x) {
    // 1/(1+e^-x); e^-x=inf -> rcp(inf)=0  (NaN-safe, no clamp needed)
    return __builtin_amdgcn_rcpf(1.f + __expf(-x));
}
__device__ __forceinline__ float fast_tanh(float x) {
    // 1 - 2/(e^{2x}+1); e=inf -> 1; e=0 -> -1  (NaN-safe)
    float e = __expf(2.f * x);
    return 1.f - 2.f * __builtin_amdgcn_rcpf(e + 1.f);
}

// ---------------------------------------------------------------------------
// Phase 0: precompute A = H^T inv(C_w) (NS x NO), M = A H (NS x NS)
// ---------------------------------------------------------------------------
__global__ void setup_consts(const float* __restrict__ H,
                             const float* __restrict__ C_w,
                             float* __restrict__ A,   // (NS,NO)
                             float* __restrict__ M)   // (NS,NS)
{
    if (threadIdx.x != 0 || blockIdx.x != 0) return;
    float W[NO_][2 * NO_];
    for (int i = 0; i < NO_; ++i) {
        for (int j = 0; j < NO_; ++j) {
            W[i][j] = C_w[i * NO_ + j];
            W[i][NO_ + j] = (i == j) ? 1.f : 0.f;
        }
    }
    for (int p = 0; p < NO_; ++p) {
        float ip = 1.f / W[p][p];
        for (int j = 0; j < 2 * NO_; ++j) W[p][j] *= ip;
        for (int i = 0; i < NO_; ++i) {
            if (i == p) continue;
            float f = W[i][p];
            for (int j = 0; j < 2 * NO_; ++j) W[i][j] -= f * W[p][j];
        }
    }
    float Aloc[NS_][NO_];
    for (int s = 0; s < NS_; ++s) {
        for (int o = 0; o < NO_; ++o) {
            float acc = 0.f;
            for (int p = 0; p < NO_; ++p) acc += H[p * NS_ + s] * W[p][NO_ + o];
            Aloc[s][o] = acc;
            A[s * NO_ + o] = acc;
        }
    }
    for (int s = 0; s < NS_; ++s) {
        for (int q = 0; q < NS_; ++q) {
            float acc = 0.f;
            for (int o = 0; o < NO_; ++o) acc += Aloc[s][o] * H[o * NS_ + q];
            M[s * NS_ + q] = acc;
        }
    }
}

// ---------------------------------------------------------------------------
// Phase 1: GRU scan. ONE WAVE per sample — zero barriers. Lane j owns h[j]
// and the three gate rows (r,z,n) of W_hh in registers (v2f pairs). h is
// broadcast through LDS: ds_write own h, then 16 uniform ds_read_b128 —
// same-wave LDS ops are in-order, no barrier needed. All dots use packed
// v_pk_fma_f32. Y prefetched 1 step ahead; h_out stores fire-and-forget.
// ---------------------------------------------------------------------------
__global__ __launch_bounds__(64, 1) void gru_kernel(
    const float* __restrict__ Y,     // (N,T,NO)
    const float* __restrict__ W_ih,  // (192,10)
    const float* __restrict__ W_hh,  // (192,64)
    const float* __restrict__ b_ih,
    const float* __restrict__ b_hh,
    float* __restrict__ h_out)       // (N*T,64)
{
    const int n = blockIdx.x;
    const int j = threadIdx.x;       // 0..63, owns h[j]

    // --- preload weights: 3 rows of W_hh (64 each) as v2f pairs ---
    v2f wr[32], wz[32], wn[32];
    {
        const v4f* wrp = (const v4f*)(W_hh + (size_t)j * HID_);
        const v4f* wzp = (const v4f*)(W_hh + (size_t)(HID_ + j) * HID_);
        const v4f* wnp = (const v4f*)(W_hh + (size_t)(2 * HID_ + j) * HID_);
#pragma unroll
        for (int k = 0; k < 16; ++k) {
            v4f t;
            t = wrp[k];
            wr[2 * k]     = __builtin_shufflevector(t, t, 0, 1);
            wr[2 * k + 1] = __builtin_shufflevector(t, t, 2, 3);
            t = wzp[k];
            wz[2 * k]     = __builtin_shufflevector(t, t, 0, 1);
            wz[2 * k + 1] = __builtin_shufflevector(t, t, 2, 3);
            t = wnp[k];
            wn[2 * k]     = __builtin_shufflevector(t, t, 0, 1);
            wn[2 * k + 1] = __builtin_shufflevector(t, t, 2, 3);
        }
    }
    // W_ih rows (10 each) as v2f (rows are 40B -> 8B aligned)
    v2f wir[5], wiz[5], win[5];
    {
        const v2f* p0 = (const v2f*)(W_ih + (size_t)j * NO_);
        const v2f* p1 = (const v2f*)(W_ih + (size_t)(HID_ + j) * NO_);
        const v2f* p2 = (const v2f*)(W_ih + (size_t)(2 * HID_ + j) * NO_);
#pragma unroll
        for (int i = 0; i < 5; ++i) { wir[i] = p0[i]; wiz[i] = p1[i]; win[i] = p2[i]; }
    }
    const float cr  = b_ih[j] + b_hh[j];                     // r-gate combined bias
    const float cz  = b_ih[HID_ + j] + b_hh[HID_ + j];       // z-gate combined bias
    const float bin = b_ih[2 * HID_ + j];
    const float bhn = b_hh[2 * HID_ + j];

    __shared__ __align__(16) float h_lds[HID_];
    float h_own = 0.f;
    h_lds[j] = 0.f;

    const float* Yn = Y + (size_t)n * T_ * NO_;
    float* hout = h_out + (size_t)n * T_ * HID_ + j;

    // prefetch y[0] (uniform broadcast load, 40B)
    v2f y[5];
    {
        const v2f* yp = (const v2f*)Yn;
#pragma unroll
        for (int i = 0; i < 5; ++i) y[i] = yp[i];
    }

    for (int t = 0; t < T_; ++t) {
        // accumulators: r,z combine x-part and h-part (sigmoid takes the sum);
        // n keeps xn separate (r multiplies only the h-part)
        v2f ar0 = {cr, 0.f},  ar1 = {0.f, 0.f};
        v2f az0 = {cz, 0.f},  az1 = {0.f, 0.f};
        v2f anx = {bin, 0.f};
        v2f an0 = {bhn, 0.f}, an1 = {0.f, 0.f};

        // input projection (from prefetched registers)
#pragma unroll
        for (int i = 0; i < 5; ++i) {
            PKFMA(ar0, wir[i], y[i]);
            PKFMA(az0, wiz[i], y[i]);
            PKFMA(anx, win[i], y[i]);
        }

        // hidden projection: uniform b128 broadcast reads of h
        const v4f* h4p = (const v4f*)h_lds;
#pragma unroll
        for (int k = 0; k < 16; ++k) {
            v4f h4 = h4p[k];
            v2f hlo = __builtin_shufflevector(h4, h4, 0, 1);
            v2f hhi = __builtin_shufflevector(h4, h4, 2, 3);
            PKFMA(ar0, wr[2 * k], hlo); PKFMA(ar1, wr[2 * k + 1], hhi);
            PKFMA(az0, wz[2 * k], hlo); PKFMA(az1, wz[2 * k + 1], hhi);
            PKFMA(an0, wn[2 * k], hlo); PKFMA(an1, wn[2 * k + 1], hhi);
        }

        // prefetch y[t+1] (latency hidden under the nonlinearity + next dots)
        {
            const int tn = (t + 1 < T_) ? t + 1 : t;
            const v2f* yp = (const v2f*)(Yn + tn * NO_);
#pragma unroll
            for (int i = 0; i < 5; ++i) y[i] = yp[i];
        }

        // gate nonlinearities (serial tail)
        v2f rv = ar0 + ar1;
        float r = fast_sigmoid(rv[0] + rv[1]);
        v2f zv = az0 + az1;
        float z = fast_sigmoid(zv[0] + zv[1]);
        float xn = anx[0] + anx[1];
        v2f nv = an0 + an1;
        float nn = fast_tanh(xn + r * (nv[0] + nv[1]));
        float h_new = nn + z * (h_own - nn);   // (1-z)*n + z*h

        h_own = h_new;
        h_lds[j] = h_new;          // same-wave LDS: in-order, no barrier
        hout[t * HID_] = h_new;    // fire-and-forget
    }
}

// ---------------------------------------------------------------------------
// Phase 2a: init output with the constant term 0.5*NS*T*log(2*pi)
// ---------------------------------------------------------------------------
__global__ void init_out(float* __restrict__ out)
{
    if (threadIdx.x == 0 && blockIdx.x == 0) {
        out[0] = 0.5f * (float)NS_ * (float)T_ * logf(2.f * 3.14159265358979323846f);
    }
}

// ---------------------------------------------------------------------------
// Phase 2b: per-(n,t) dense head + information-form Kalman + log-pdf terms.
// ---------------------------------------------------------------------------
__global__ __launch_bounds__(256) void post_kernel(
    const float* __restrict__ h_out,  // (N*T,64)
    const float* __restrict__ Y,      // (N,T,NO)
    const float* __restrict__ X,      // (N,T,NS)
    const float* __restrict__ W_fc, const float* __restrict__ b_fc,
    const float* __restrict__ W_mean, const float* __restrict__ b_mean,
    const float* __restrict__ W_vars, const float* __restrict__ b_vars,
    const float* __restrict__ Ac,     // (NS,NO)
    const float* __restrict__ Mc,     // (NS,NS)
    float* __restrict__ out)
{
    __shared__ float sWfc[DENSE_][HID_];
    __shared__ float sWm[NS_][DENSE_];
    __shared__ float sWv[NS_][DENSE_];
    __shared__ float sA[NS_][NO_];
    __shared__ float sM[NS_][NS_];
    __shared__ float sbfc[DENSE_], sbm[NS_], sbv[NS_];
    __shared__ float wsum[4];

    for (int i = threadIdx.x; i < DENSE_ * HID_; i += blockDim.x)
        sWfc[i / HID_][i % HID_] = W_fc[i];
    for (int i = threadIdx.x; i < NS_ * DENSE_; i += blockDim.x) {
        sWm[i / DENSE_][i % DENSE_] = W_mean[i];
        sWv[i / DENSE_][i % DENSE_] = W_vars[i];
    }
    for (int i = threadIdx.x; i < NS_ * NO_; i += blockDim.x) sA[i / NO_][i % NO_] = Ac[i];
    for (int i = threadIdx.x; i < NS_ * NS_; i += blockDim.x) sM[i / NS_][i % NS_] = Mc[i];
    if (threadIdx.x < DENSE_) sbfc[threadIdx.x] = b_fc[threadIdx.x];
    if (threadIdx.x < NS_) { sbm[threadIdx.x] = b_mean[threadIdx.x]; sbv[threadIdx.x] = b_vars[threadIdx.x]; }
    __syncthreads();

    const int task = blockIdx.x * blockDim.x + threadIdx.x;
    float contrib = 0.f;
    if (task < N_ * T_) {
        float y[DENSE_];
#pragma unroll
        for (int d = 0; d < DENSE_; ++d) y[d] = sbfc[d];
        const float* hp = h_out + (size_t)task * HID_;
#pragma unroll
        for (int k = 0; k < HID_; k += 4) {
            float4 h4 = *(const float4*)(hp + k);
#pragma unroll
            for (int d = 0; d < DENSE_; ++d) {
                y[d] += sWfc[d][k + 0] * h4.x + sWfc[d][k + 1] * h4.y +
                        sWfc[d][k + 2] * h4.z + sWfc[d][k + 3] * h4.w;
            }
        }
#pragma unroll
        for (int d = 0; d < DENSE_; ++d) y[d] = fmaxf(y[d], 0.f);

        float mu[NS_], vinv[NS_];
#pragma unroll
        for (int s = 0; s < NS_; ++s) {
            float am = sbm[s], av = sbv[s];
#pragma unroll
            for (int d = 0; d < DENSE_; ++d) { am += sWm[s][d] * y[d]; av += sWv[s][d] * y[d]; }
            mu[s] = am;
            float sp = (av > 20.f) ? av : log1pf(__expf(av));  // softplus
            vinv[s] = 1.f / sp;
        }

        const float* yo = Y + (size_t)task * NO_;
        const float* xo = X + (size_t)task * NS_;
        float b[NS_];
#pragma unroll
        for (int s = 0; s < NS_; ++s) {
            float acc = vinv[s] * mu[s];
#pragma unroll
            for (int o = 0; o < NO_; ++o) acc += sA[s][o] * yo[o];
            b[s] = acc;
        }

        // L_inv = M + diag(v^-1), Cholesky
        float L[NS_][NS_];
#pragma unroll
        for (int i = 0; i < NS_; ++i)
#pragma unroll
            for (int jj = 0; jj <= i; ++jj)
                L[i][jj] = sM[i][jj] + ((i == jj) ? vinv[i] : 0.f);
        float ld = 0.f;
        float dinv[NS_];
#pragma unroll
        for (int jj = 0; jj < NS_; ++jj) {
            float s = L[jj][jj];
#pragma unroll
            for (int k = 0; k < jj; ++k) s -= L[jj][k] * L[jj][k];
            float d = sqrtf(s);
            ld += __logf(d);
            float di = 1.f / d;
            dinv[jj] = di;
            L[jj][jj] = d;
#pragma unroll
            for (int i = jj + 1; i < NS_; ++i) {
                float t2 = L[i][jj];
#pragma unroll
                for (int k = 0; k < jj; ++k) t2 -= L[i][k] * L[jj][k];
                L[i][jj] = t2 * di;
            }
        }
        ld *= 2.f;

        float w[NS_];
#pragma unroll
        for (int i = 0; i < NS_; ++i) {
            float s = b[i];
#pragma unroll
            for (int k = 0; k < i; ++k) s -= L[i][k] * w[k];
            w[i] = s * dinv[i];
        }
        float mpost[NS_];
#pragma unroll
        for (int ii = NS_ - 1; ii >= 0; --ii) {
            float s = w[ii];
#pragma unroll
            for (int k = ii + 1; k < NS_; ++k) s -= L[k][ii] * mpost[k];
            mpost[ii] = s * dinv[ii];
        }

        float diff[NS_];
#pragma unroll
        for (int s = 0; s < NS_; ++s) diff[s] = xo[s] - mpost[s];
        float quad = 0.f;
#pragma unroll
        for (int jj = 0; jj < NS_; ++jj) {
            float u = 0.f;
#pragma unroll
            for (int i = jj; i < NS_; ++i) u += L[i][jj] * diff[i];
            quad += u * u;
        }

        contrib = 0.5f * (ld - quad) * (1.0f / (float)N_);
    }

#pragma unroll
    for (int off = 32; off; off >>= 1) contrib += __shfl_down(contrib, off);
    const int wid = threadIdx.x >> 6;
    if ((threadIdx.x & 63) == 0) wsum[wid] = contrib;
    __syncthreads();
    if (threadIdx.x == 0) {
        float s = 0.f;
#pragma unroll
        for (int i = 0; i < 4; ++i) s += wsum[i];
        atomicAdd(out, s);
    }
}

// ---------------------------------------------------------------------------
extern "C" void kernel_launch(void* const* d_in, const int* in_sizes, int n_in,
                              void* d_out, int out_size, void* d_ws, size_t ws_size,
                              hipStream_t stream)
{
    const float* Y      = (const float*)d_in[0];
    const float* X      = (const float*)d_in[1];
    const float* H      = (const float*)d_in[2];
    const float* C_w    = (const float*)d_in[4];
    const float* W_ih   = (const float*)d_in[5];
    const float* W_hh   = (const float*)d_in[6];
    const float* b_ih   = (const float*)d_in[7];
    const float* b_hh   = (const float*)d_in[8];
    const float* W_fc   = (const float*)d_in[9];
    const float* b_fc   = (const float*)d_in[10];
    const float* W_mean = (const float*)d_in[11];
    const float* b_mean = (const float*)d_in[12];
    const float* W_vars = (const float*)d_in[13];
    const float* b_vars = (const float*)d_in[14];
    float* out = (float*)d_out;

    float* h_out = (float*)d_ws;                       // 32.77 MB
    float* Ac = h_out + (size_t)N_ * T_ * HID_;
    float* Mc = Ac + NS_ * NO_;

    hipLaunchKernelGGL(setup_consts, dim3(1), dim3(64), 0, stream, H, C_w, Ac, Mc);
    hipLaunchKernelGGL(gru_kernel, dim3(N_), dim3(64), 0, stream,
                       Y, W_ih, W_hh, b_ih, b_hh, h_out);
    hipLaunchKernelGGL(init_out, dim3(1), dim3(1), 0, stream, out);
    hipLaunchKernelGGL(post_kernel, dim3((N_ * T_ + 255) / 256), dim3(256), 0, stream,
                       h_out, Y, X, W_fc, b_fc, W_mean, b_mean, W_vars, b_vars,
                       Ac, Mc, out);
}

// Round 4
// 751.642 us; speedup vs baseline: 1.3197x; 1.3197x over previous
//
#include <hip/hip_runtime.h>
#include <math.h>

// Problem constants (from reference)
#define N_    128
#define T_    1000
#define NS_   10
#define NO_   10
#define HID_  64
#define DENSE_ 32

typedef float v2f __attribute__((ext_vector_type(2)));
typedef float v4f __attribute__((ext_vector_type(4)));

// Opaque def: pins a preloaded value as register-resident (prevents the
// allocator from sinking the load into the loop / rematerializing).
#define KEEP2(a, b) asm volatile("" : "+v"(a), "+v"(b))

__device__ __forceinline__ float fast_sigmoid(float x) {
    // 1/(1+e^-x); e^-x=inf -> rcp(inf)=0  (NaN-safe, no clamp needed)
    return __builtin_amdgcn_rcpf(1.f + __expf(-x));
}
__device__ __forceinline__ float fast_tanh(float x) {
    // 1 - 2/(e^{2x}+1); e=inf -> 1; e=0 -> -1  (NaN-safe)
    float e = __expf(2.f * x);
    return 1.f - 2.f * __builtin_amdgcn_rcpf(e + 1.f);
}

// ---------------------------------------------------------------------------
// Phase 0: precompute A = H^T inv(C_w) (NS x NO), M = A H (NS x NS)
// ---------------------------------------------------------------------------
__global__ void setup_consts(const float* __restrict__ H,
                             const float* __restrict__ C_w,
                             float* __restrict__ A,   // (NS,NO)
                             float* __restrict__ M)   // (NS,NS)
{
    if (threadIdx.x != 0 || blockIdx.x != 0) return;
    float W[NO_][2 * NO_];
    for (int i = 0; i < NO_; ++i) {
        for (int j = 0; j < NO_; ++j) {
            W[i][j] = C_w[i * NO_ + j];
            W[i][NO_ + j] = (i == j) ? 1.f : 0.f;
        }
    }
    for (int p = 0; p < NO_; ++p) {
        float ip = 1.f / W[p][p];
        for (int j = 0; j < 2 * NO_; ++j) W[p][j] *= ip;
        for (int i = 0; i < NO_; ++i) {
            if (i == p) continue;
            float f = W[i][p];
            for (int j = 0; j < 2 * NO_; ++j) W[i][j] -= f * W[p][j];
        }
    }
    float Aloc[NS_][NO_];
    for (int s = 0; s < NS_; ++s) {
        for (int o = 0; o < NO_; ++o) {
            float acc = 0.f;
            for (int p = 0; p < NO_; ++p) acc += H[p * NS_ + s] * W[p][NO_ + o];
            Aloc[s][o] = acc;
            A[s * NO_ + o] = acc;
        }
    }
    for (int s = 0; s < NS_; ++s) {
        for (int q = 0; q < NS_; ++q) {
            float acc = 0.f;
            for (int o = 0; o < NO_; ++o) acc += Aloc[s][o] * H[o * NS_ + q];
            M[s * NS_ + q] = acc;
        }
    }
}

// ---------------------------------------------------------------------------
// Phase 1: GRU scan. ONE WAVE per sample — zero barriers. Lane j owns h[j]
// and the three gate rows (r,z,n) of W_hh pinned in registers (~240 VGPRs;
// waves_per_eu(1,1) grants the 512 budget). h broadcast through LDS:
// ds_write own h, then 16 uniform ds_read_b128 — same-wave LDS ops are
// in-order, no barrier. Dots vectorize to v_pk_fma_f32.
// ---------------------------------------------------------------------------
__global__
__attribute__((amdgpu_flat_work_group_size(64, 64), amdgpu_waves_per_eu(1, 1)))
void gru_kernel(
    const float* __restrict__ Y,     // (N,T,NO)
    const float* __restrict__ W_ih,  // (192,10)
    const float* __restrict__ W_hh,  // (192,64)
    const float* __restrict__ b_ih,
    const float* __restrict__ b_hh,
    float* __restrict__ h_out)       // (N*T,64)
{
    const int n = blockIdx.x;
    const int j = threadIdx.x;       // 0..63, owns h[j]

    // --- preload weights: 3 rows of W_hh (64 each) as v2f pairs ---
    v2f wr[32], wz[32], wn[32];
    {
        const v4f* wrp = (const v4f*)(W_hh + (size_t)j * HID_);
        const v4f* wzp = (const v4f*)(W_hh + (size_t)(HID_ + j) * HID_);
        const v4f* wnp = (const v4f*)(W_hh + (size_t)(2 * HID_ + j) * HID_);
#pragma unroll
        for (int k = 0; k < 16; ++k) {
            v4f t;
            t = wrp[k];
            wr[2 * k]     = __builtin_shufflevector(t, t, 0, 1);
            wr[2 * k + 1] = __builtin_shufflevector(t, t, 2, 3);
            t = wzp[k];
            wz[2 * k]     = __builtin_shufflevector(t, t, 0, 1);
            wz[2 * k + 1] = __builtin_shufflevector(t, t, 2, 3);
            t = wnp[k];
            wn[2 * k]     = __builtin_shufflevector(t, t, 0, 1);
            wn[2 * k + 1] = __builtin_shufflevector(t, t, 2, 3);
        }
    }
    // W_ih rows (10 each) as v2f (rows are 40B -> 8B aligned)
    v2f wir[5], wiz[5], win[5];
    {
        const v2f* p0 = (const v2f*)(W_ih + (size_t)j * NO_);
        const v2f* p1 = (const v2f*)(W_ih + (size_t)(HID_ + j) * NO_);
        const v2f* p2 = (const v2f*)(W_ih + (size_t)(2 * HID_ + j) * NO_);
#pragma unroll
        for (int i = 0; i < 5; ++i) { wir[i] = p0[i]; wiz[i] = p1[i]; win[i] = p2[i]; }
    }
    // Pin everything register-resident (opaque defs outside the loop).
#pragma unroll
    for (int k = 0; k < 32; ++k) { KEEP2(wr[k], wz[k]); asm volatile("" : "+v"(wn[k])); }
#pragma unroll
    for (int i = 0; i < 5; ++i) { KEEP2(wir[i], wiz[i]); asm volatile("" : "+v"(win[i])); }

    const float cr  = b_ih[j] + b_hh[j];                     // r-gate combined bias
    const float cz  = b_ih[HID_ + j] + b_hh[HID_ + j];       // z-gate combined bias
    const float bin = b_ih[2 * HID_ + j];
    const float bhn = b_hh[2 * HID_ + j];

    __shared__ __align__(16) float h_lds[HID_];
    float h_own = 0.f;
    h_lds[j] = 0.f;

    const float* Yn = Y + (size_t)n * T_ * NO_;
    float* hout = h_out + (size_t)n * T_ * HID_ + j;

    // prefetch y[0] (uniform broadcast load, 40B)
    v2f y[5];
    {
        const v2f* yp = (const v2f*)Yn;
#pragma unroll
        for (int i = 0; i < 5; ++i) y[i] = yp[i];
    }

    for (int t = 0; t < T_; ++t) {
        // accumulators: r,z combine x-part and h-part (sigmoid takes the sum);
        // n keeps xn separate (r multiplies only the h-part)
        v2f ar0 = {cr, 0.f},  ar1 = {0.f, 0.f};
        v2f az0 = {cz, 0.f},  az1 = {0.f, 0.f};
        v2f anx = {bin, 0.f};
        v2f an0 = {bhn, 0.f}, an1 = {0.f, 0.f};

        // input projection (from prefetched registers)
#pragma unroll
        for (int i = 0; i < 5; ++i) {
            ar0 += wir[i] * y[i];
            az0 += wiz[i] * y[i];
            anx += win[i] * y[i];
        }

        // hidden projection: uniform b128 broadcast reads of h
        const v4f* h4p = (const v4f*)h_lds;
#pragma unroll
        for (int k = 0; k < 16; ++k) {
            v4f h4 = h4p[k];
            v2f hlo = __builtin_shufflevector(h4, h4, 0, 1);
            v2f hhi = __builtin_shufflevector(h4, h4, 2, 3);
            ar0 += wr[2 * k] * hlo;  ar1 += wr[2 * k + 1] * hhi;
            az0 += wz[2 * k] * hlo;  az1 += wz[2 * k + 1] * hhi;
            an0 += wn[2 * k] * hlo;  an1 += wn[2 * k + 1] * hhi;
        }

        // prefetch y[t+1] (latency hidden under the dots / tail)
        {
            const int tn = (t + 1 < T_) ? t + 1 : t;
            const v2f* yp = (const v2f*)(Yn + tn * NO_);
#pragma unroll
            for (int i = 0; i < 5; ++i) y[i] = yp[i];
        }

        // gate nonlinearities (serial tail)
        v2f rv = ar0 + ar1;
        float r = fast_sigmoid(rv[0] + rv[1]);
        v2f zv = az0 + az1;
        float z = fast_sigmoid(zv[0] + zv[1]);
        float xn = anx[0] + anx[1];
        v2f nv = an0 + an1;
        float nn = fast_tanh(xn + r * (nv[0] + nv[1]));
        float h_new = nn + z * (h_own - nn);   // (1-z)*n + z*h

        h_own = h_new;
        h_lds[j] = h_new;          // same-wave LDS: in-order, no barrier
        hout[t * HID_] = h_new;    // fire-and-forget
    }
}

// ---------------------------------------------------------------------------
// Phase 2a: init output with the constant term 0.5*NS*T*log(2*pi)
// ---------------------------------------------------------------------------
__global__ void init_out(float* __restrict__ out)
{
    if (threadIdx.x == 0 && blockIdx.x == 0) {
        out[0] = 0.5f * (float)NS_ * (float)T_ * logf(2.f * 3.14159265358979323846f);
    }
}

// ---------------------------------------------------------------------------
// Phase 2b: per-(n,t) dense head + information-form Kalman + log-pdf terms.
// ---------------------------------------------------------------------------
__global__ __launch_bounds__(256) void post_kernel(
    const float* __restrict__ h_out,  // (N*T,64)
    const float* __restrict__ Y,      // (N,T,NO)
    const float* __restrict__ X,      // (N,T,NS)
    const float* __restrict__ W_fc, const float* __restrict__ b_fc,
    const float* __restrict__ W_mean, const float* __restrict__ b_mean,
    const float* __restrict__ W_vars, const float* __restrict__ b_vars,
    const float* __restrict__ Ac,     // (NS,NO)
    const float* __restrict__ Mc,     // (NS,NS)
    float* __restrict__ out)
{
    __shared__ float sWfc[DENSE_][HID_];
    __shared__ float sWm[NS_][DENSE_];
    __shared__ float sWv[NS_][DENSE_];
    __shared__ float sA[NS_][NO_];
    __shared__ float sM[NS_][NS_];
    __shared__ float sbfc[DENSE_], sbm[NS_], sbv[NS_];
    __shared__ float wsum[4];

    for (int i = threadIdx.x; i < DENSE_ * HID_; i += blockDim.x)
        sWfc[i / HID_][i % HID_] = W_fc[i];
    for (int i = threadIdx.x; i < NS_ * DENSE_; i += blockDim.x) {
        sWm[i / DENSE_][i % DENSE_] = W_mean[i];
        sWv[i / DENSE_][i % DENSE_] = W_vars[i];
    }
    for (int i = threadIdx.x; i < NS_ * NO_; i += blockDim.x) sA[i / NO_][i % NO_] = Ac[i];
    for (int i = threadIdx.x; i < NS_ * NS_; i += blockDim.x) sM[i / NS_][i % NS_] = Mc[i];
    if (threadIdx.x < DENSE_) sbfc[threadIdx.x] = b_fc[threadIdx.x];
    if (threadIdx.x < NS_) { sbm[threadIdx.x] = b_mean[threadIdx.x]; sbv[threadIdx.x] = b_vars[threadIdx.x]; }
    __syncthreads();

    const int task = blockIdx.x * blockDim.x + threadIdx.x;
    float contrib = 0.f;
    if (task < N_ * T_) {
        float y[DENSE_];
#pragma unroll
        for (int d = 0; d < DENSE_; ++d) y[d] = sbfc[d];
        const float* hp = h_out + (size_t)task * HID_;
#pragma unroll
        for (int k = 0; k < HID_; k += 4) {
            float4 h4 = *(const float4*)(hp + k);
#pragma unroll
            for (int d = 0; d < DENSE_; ++d) {
                y[d] += sWfc[d][k + 0] * h4.x + sWfc[d][k + 1] * h4.y +
                        sWfc[d][k + 2] * h4.z + sWfc[d][k + 3] * h4.w;
            }
        }
#pragma unroll
        for (int d = 0; d < DENSE_; ++d) y[d] = fmaxf(y[d], 0.f);

        float mu[NS_], vinv[NS_];
#pragma unroll
        for (int s = 0; s < NS_; ++s) {
            float am = sbm[s], av = sbv[s];
#pragma unroll
            for (int d = 0; d < DENSE_; ++d) { am += sWm[s][d] * y[d]; av += sWv[s][d] * y[d]; }
            mu[s] = am;
            float sp = (av > 20.f) ? av : log1pf(__expf(av));  // softplus
            vinv[s] = 1.f / sp;
        }

        const float* yo = Y + (size_t)task * NO_;
        const float* xo = X + (size_t)task * NS_;
        float b[NS_];
#pragma unroll
        for (int s = 0; s < NS_; ++s) {
            float acc = vinv[s] * mu[s];
#pragma unroll
            for (int o = 0; o < NO_; ++o) acc += sA[s][o] * yo[o];
            b[s] = acc;
        }

        // L_inv = M + diag(v^-1), Cholesky
        float L[NS_][NS_];
#pragma unroll
        for (int i = 0; i < NS_; ++i)
#pragma unroll
            for (int jj = 0; jj <= i; ++jj)
                L[i][jj] = sM[i][jj] + ((i == jj) ? vinv[i] : 0.f);
        float ld = 0.f;
        float dinv[NS_];
#pragma unroll
        for (int jj = 0; jj < NS_; ++jj) {
            float s = L[jj][jj];
#pragma unroll
            for (int k = 0; k < jj; ++k) s -= L[jj][k] * L[jj][k];
            float d = sqrtf(s);
            ld += __logf(d);
            float di = 1.f / d;
            dinv[jj] = di;
            L[jj][jj] = d;
#pragma unroll
            for (int i = jj + 1; i < NS_; ++i) {
                float t2 = L[i][jj];
#pragma unroll
                for (int k = 0; k < jj; ++k) t2 -= L[i][k] * L[jj][k];
                L[i][jj] = t2 * di;
            }
        }
        ld *= 2.f;

        float w[NS_];
#pragma unroll
        for (int i = 0; i < NS_; ++i) {
            float s = b[i];
#pragma unroll
            for (int k = 0; k < i; ++k) s -= L[i][k] * w[k];
            w[i] = s * dinv[i];
        }
        float mpost[NS_];
#pragma unroll
        for (int ii = NS_ - 1; ii >= 0; --ii) {
            float s = w[ii];
#pragma unroll
            for (int k = ii + 1; k < NS_; ++k) s -= L[k][ii] * mpost[k];
            mpost[ii] = s * dinv[ii];
        }

        float diff[NS_];
#pragma unroll
        for (int s = 0; s < NS_; ++s) diff[s] = xo[s] - mpost[s];
        float quad = 0.f;
#pragma unroll
        for (int jj = 0; jj < NS_; ++jj) {
            float u = 0.f;
#pragma unroll
            for (int i = jj; i < NS_; ++i) u += L[i][jj] * diff[i];
            quad += u * u;
        }

        contrib = 0.5f * (ld - quad) * (1.0f / (float)N_);
    }

#pragma unroll
    for (int off = 32; off; off >>= 1) contrib += __shfl_down(contrib, off);
    const int wid = threadIdx.x >> 6;
    if ((threadIdx.x & 63) == 0) wsum[wid] = contrib;
    __syncthreads();
    if (threadIdx.x == 0) {
        float s = 0.f;
#pragma unroll
        for (int i = 0; i < 4; ++i) s += wsum[i];
        atomicAdd(out, s);
    }
}

// ---------------------------------------------------------------------------
extern "C" void kernel_launch(void* const* d_in, const int* in_sizes, int n_in,
                              void* d_out, int out_size, void* d_ws, size_t ws_size,
                              hipStream_t stream)
{
    const float* Y      = (const float*)d_in[0];
    const float* X      = (const float*)d_in[1];
    const float* H      = (const float*)d_in[2];
    const float* C_w    = (const float*)d_in[4];
    const float* W_ih   = (const float*)d_in[5];
    const float* W_hh   = (const float*)d_in[6];
    const float* b_ih   = (const float*)d_in[7];
    const float* b_hh   = (const float*)d_in[8];
    const float* W_fc   = (const float*)d_in[9];
    const float* b_fc   = (const float*)d_in[10];
    const float* W_mean = (const float*)d_in[11];
    const float* b_mean = (const float*)d_in[12];
    const float* W_vars = (const float*)d_in[13];
    const float* b_vars = (const float*)d_in[14];
    float* out = (float*)d_out;

    float* h_out = (float*)d_ws;                       // 32.77 MB
    float* Ac = h_out + (size_t)N_ * T_ * HID_;
    float* Mc = Ac + NS_ * NO_;

    hipLaunchKernelGGL(setup_consts, dim3(1), dim3(64), 0, stream, H, C_w, Ac, Mc);
    hipLaunchKernelGGL(gru_kernel, dim3(N_), dim3(64), 0, stream,
                       Y, W_ih, W_hh, b_ih, b_hh, h_out);
    hipLaunchKernelGGL(init_out, dim3(1), dim3(1), 0, stream, out);
    hipLaunchKernelGGL(post_kernel, dim3((N_ * T_ + 255) / 256), dim3(256), 0, stream,
                       h_out, Y, X, W_fc, b_fc, W_mean, b_mean, W_vars, b_vars,
                       Ac, Mc, out);
}

// Round 5
// 684.695 us; speedup vs baseline: 1.4487x; 1.0978x over previous
//
#include <hip/hip_runtime.h>
#include <math.h>

// Problem constants (from reference)
#define N_    128
#define T_    1000
#define NS_   10
#define NO_   10
#define HID_  64
#define G3_   192
#define DENSE_ 32

typedef float v2f __attribute__((ext_vector_type(2)));
typedef float v4f __attribute__((ext_vector_type(4)));

// Barrier that waits only on LDS ops (global h_out stores are consumed by a
// later dispatch, never by another wave in-kernel -> no vmcnt drain).
#define LDS_BARRIER() asm volatile("s_waitcnt lgkmcnt(0)\n\ts_barrier" ::: "memory")

__device__ __forceinline__ float fast_sigmoid(float x) {
    return __builtin_amdgcn_rcpf(1.f + __expf(-x));   // NaN-safe
}
__device__ __forceinline__ float fast_tanh(float x) {
    float e = __expf(2.f * x);
    return 1.f - 2.f * __builtin_amdgcn_rcpf(e + 1.f); // NaN-safe
}

// ---------------------------------------------------------------------------
// Phase 0: precompute A = H^T inv(C_w) (NS x NO), M = A H (NS x NS)
// ---------------------------------------------------------------------------
__global__ void setup_consts(const float* __restrict__ H,
                             const float* __restrict__ C_w,
                             float* __restrict__ A,   // (NS,NO)
                             float* __restrict__ M)   // (NS,NS)
{
    if (threadIdx.x != 0 || blockIdx.x != 0) return;
    float W[NO_][2 * NO_];
    for (int i = 0; i < NO_; ++i) {
        for (int j = 0; j < NO_; ++j) {
            W[i][j] = C_w[i * NO_ + j];
            W[i][NO_ + j] = (i == j) ? 1.f : 0.f;
        }
    }
    for (int p = 0; p < NO_; ++p) {
        float ip = 1.f / W[p][p];
        for (int j = 0; j < 2 * NO_; ++j) W[p][j] *= ip;
        for (int i = 0; i < NO_; ++i) {
            if (i == p) continue;
            float f = W[i][p];
            for (int j = 0; j < 2 * NO_; ++j) W[i][j] -= f * W[p][j];
        }
    }
    float Aloc[NS_][NO_];
    for (int s = 0; s < NS_; ++s) {
        for (int o = 0; o < NO_; ++o) {
            float acc = 0.f;
            for (int p = 0; p < NO_; ++p) acc += H[p * NS_ + s] * W[p][NO_ + o];
            Aloc[s][o] = acc;
            A[s * NO_ + o] = acc;
        }
    }
    for (int s = 0; s < NS_; ++s) {
        for (int q = 0; q < NS_; ++q) {
            float acc = 0.f;
            for (int o = 0; o < NO_; ++o) acc += Aloc[s][o] * H[o * NS_ + q];
            M[s * NS_ + q] = acc;
        }
    }
}

// ---------------------------------------------------------------------------
// Phase 1: GRU scan. 3 waves per sample = gates r/z/n; lane owns one gate row
// (64+10 weights ~ 105 VGPRs total demand -> no spills). Per step:
//   - every wave: own-gate dot from its PRIVATE h copy in LDS (written only
//     by itself -> same-wave in-order, no barrier needed for h)
//   - write gate value(s) to double-buffered gbuf[t&1][j][4] = {r,z,xn,hn}
//   - ONE LDS-only barrier
//   - every wave redundantly: ds_read_b128 gbuf -> tanh + h update -> write
//     own h copy; wave 0 also stores h_out (fire-and-forget)
// Double buffering of gbuf bounds inter-wave skew (max 1 step ahead, enforced
// by the single barrier) -> no write/read collision.
// ---------------------------------------------------------------------------
__global__ __launch_bounds__(G3_) void gru_kernel(
    const float* __restrict__ Y,     // (N,T,NO)
    const float* __restrict__ W_ih,  // (192,10)
    const float* __restrict__ W_hh,  // (192,64)
    const float* __restrict__ b_ih,
    const float* __restrict__ b_hh,
    float* __restrict__ h_out)       // (N*T,64)
{
    const int n = blockIdx.x;
    const int g = threadIdx.x >> 6;      // 0=r, 1=z, 2=n (wave-uniform)
    const int j = threadIdx.x & 63;
    const int row = threadIdx.x;         // gate row in [0,192)

    // --- weights for this gate row ---
    v2f whh[32];
    {
        const v4f* wp = (const v4f*)(W_hh + (size_t)row * HID_);
#pragma unroll
        for (int k = 0; k < 16; ++k) {
            v4f t = wp[k];
            whh[2 * k]     = __builtin_shufflevector(t, t, 0, 1);
            whh[2 * k + 1] = __builtin_shufflevector(t, t, 2, 3);
        }
    }
    v2f wih[5];
    {
        const v2f* p = (const v2f*)(W_ih + (size_t)row * NO_);
#pragma unroll
        for (int i = 0; i < 5; ++i) wih[i] = p[i];
    }
    const float bi = b_ih[row];
    const float bh = b_hh[row];
    // r,z: bias folds into one accumulator; n: keep x/h parts separate
    const float bx = (g == 2) ? bi : (bi + bh);
    const float bhp = (g == 2) ? bh : 0.f;

    __shared__ __align__(16) float h_copy[3][HID_];   // private per-wave h
    __shared__ __align__(16) float gbuf[2][HID_][4];  // parity, j, {r,z,xn,hn}

    h_copy[g][j] = 0.f;    // own copy: same-wave in-order vs later reads
    float h_own = 0.f;

    const float* Yn = Y + (size_t)n * T_ * NO_;
    float* hout = h_out + (size_t)n * T_ * HID_ + j;

    // prefetch y[0] (uniform broadcast, 40B)
    v2f y[5];
    {
        const v2f* yp = (const v2f*)Yn;
#pragma unroll
        for (int i = 0; i < 5; ++i) y[i] = yp[i];
    }

    for (int t = 0; t < T_; ++t) {
        const int p = t & 1;

        // x-projection (registers)
        v2f ax = {bx, 0.f};
#pragma unroll
        for (int i = 0; i < 5; ++i) ax += wih[i] * y[i];

        // h-projection: 16 uniform b128 broadcast reads of own h copy
        v2f ah0 = {bhp, 0.f}, ah1 = {0.f, 0.f};
        const v4f* h4p = (const v4f*)h_copy[g];
#pragma unroll
        for (int k = 0; k < 16; ++k) {
            v4f h4 = h4p[k];
            ah0 += whh[2 * k]     * __builtin_shufflevector(h4, h4, 0, 1);
            ah1 += whh[2 * k + 1] * __builtin_shufflevector(h4, h4, 2, 3);
        }

        // prefetch y[t+1]
        {
            const int tn = (t + 1 < T_) ? t + 1 : t;
            const v2f* yp = (const v2f*)(Yn + tn * NO_);
#pragma unroll
            for (int i = 0; i < 5; ++i) y[i] = yp[i];
        }

        const float xs = ax[0] + ax[1];
        v2f ahv = ah0 + ah1;
        const float hs = ahv[0] + ahv[1];

        if (g == 0)      gbuf[p][j][0] = fast_sigmoid(xs + hs);
        else if (g == 1) gbuf[p][j][1] = fast_sigmoid(xs + hs);
        else {           // n-gate: publish x-part and h-part (r applied later)
            v2f xnhn = {xs, hs};
            *(v2f*)&gbuf[p][j][2] = xnhn;
        }
        LDS_BARRIER();

        // redundant combine on every wave (removes the second barrier)
        v4f gv = *(const v4f*)gbuf[p][j];   // {r, z, xn, hn} — conflict-free b128
        const float r = gv[0], z = gv[1];
        const float nn = fast_tanh(gv[2] + r * gv[3]);
        const float h_new = nn + z * (h_own - nn);
        h_own = h_new;
        h_copy[g][j] = h_new;               // own copy only
        if (g == 0) hout[t * HID_] = h_new; // fire-and-forget
    }
}

// ---------------------------------------------------------------------------
// Phase 2a: init output with the constant term 0.5*NS*T*log(2*pi)
// ---------------------------------------------------------------------------
__global__ void init_out(float* __restrict__ out)
{
    if (threadIdx.x == 0 && blockIdx.x == 0) {
        out[0] = 0.5f * (float)NS_ * (float)T_ * logf(2.f * 3.14159265358979323846f);
    }
}

// ---------------------------------------------------------------------------
// Phase 2b: per-(n,t) dense head + information-form Kalman + log-pdf terms.
// ---------------------------------------------------------------------------
__global__ __launch_bounds__(256) void post_kernel(
    const float* __restrict__ h_out,  // (N*T,64)
    const float* __restrict__ Y,      // (N,T,NO)
    const float* __restrict__ X,      // (N,T,NS)
    const float* __restrict__ W_fc, const float* __restrict__ b_fc,
    const float* __restrict__ W_mean, const float* __restrict__ b_mean,
    const float* __restrict__ W_vars, const float* __restrict__ b_vars,
    const float* __restrict__ Ac,     // (NS,NO)
    const float* __restrict__ Mc,     // (NS,NS)
    float* __restrict__ out)
{
    __shared__ float sWfc[DENSE_][HID_];
    __shared__ float sWm[NS_][DENSE_];
    __shared__ float sWv[NS_][DENSE_];
    __shared__ float sA[NS_][NO_];
    __shared__ float sM[NS_][NS_];
    __shared__ float sbfc[DENSE_], sbm[NS_], sbv[NS_];
    __shared__ float wsum[4];

    for (int i = threadIdx.x; i < DENSE_ * HID_; i += blockDim.x)
        sWfc[i / HID_][i % HID_] = W_fc[i];
    for (int i = threadIdx.x; i < NS_ * DENSE_; i += blockDim.x) {
        sWm[i / DENSE_][i % DENSE_] = W_mean[i];
        sWv[i / DENSE_][i % DENSE_] = W_vars[i];
    }
    for (int i = threadIdx.x; i < NS_ * NO_; i += blockDim.x) sA[i / NO_][i % NO_] = Ac[i];
    for (int i = threadIdx.x; i < NS_ * NS_; i += blockDim.x) sM[i / NS_][i % NS_] = Mc[i];
    if (threadIdx.x < DENSE_) sbfc[threadIdx.x] = b_fc[threadIdx.x];
    if (threadIdx.x < NS_) { sbm[threadIdx.x] = b_mean[threadIdx.x]; sbv[threadIdx.x] = b_vars[threadIdx.x]; }
    __syncthreads();

    const int task = blockIdx.x * blockDim.x + threadIdx.x;
    float contrib = 0.f;
    if (task < N_ * T_) {
        float y[DENSE_];
#pragma unroll
        for (int d = 0; d < DENSE_; ++d) y[d] = sbfc[d];
        const float* hp = h_out + (size_t)task * HID_;
#pragma unroll
        for (int k = 0; k < HID_; k += 4) {
            float4 h4 = *(const float4*)(hp + k);
#pragma unroll
            for (int d = 0; d < DENSE_; ++d) {
                y[d] += sWfc[d][k + 0] * h4.x + sWfc[d][k + 1] * h4.y +
                        sWfc[d][k + 2] * h4.z + sWfc[d][k + 3] * h4.w;
            }
        }
#pragma unroll
        for (int d = 0; d < DENSE_; ++d) y[d] = fmaxf(y[d], 0.f);

        float mu[NS_], vinv[NS_];
#pragma unroll
        for (int s = 0; s < NS_; ++s) {
            float am = sbm[s], av = sbv[s];
#pragma unroll
            for (int d = 0; d < DENSE_; ++d) { am += sWm[s][d] * y[d]; av += sWv[s][d] * y[d]; }
            mu[s] = am;
            float sp = (av > 20.f) ? av : log1pf(__expf(av));  // softplus
            vinv[s] = 1.f / sp;
        }

        const float* yo = Y + (size_t)task * NO_;
        const float* xo = X + (size_t)task * NS_;
        float b[NS_];
#pragma unroll
        for (int s = 0; s < NS_; ++s) {
            float acc = vinv[s] * mu[s];
#pragma unroll
            for (int o = 0; o < NO_; ++o) acc += sA[s][o] * yo[o];
            b[s] = acc;
        }

        // L_inv = M + diag(v^-1), Cholesky
        float L[NS_][NS_];
#pragma unroll
        for (int i = 0; i < NS_; ++i)
#pragma unroll
            for (int jj = 0; jj <= i; ++jj)
                L[i][jj] = sM[i][jj] + ((i == jj) ? vinv[i] : 0.f);
        float ld = 0.f;
        float dinv[NS_];
#pragma unroll
        for (int jj = 0; jj < NS_; ++jj) {
            float s = L[jj][jj];
#pragma unroll
            for (int k = 0; k < jj; ++k) s -= L[jj][k] * L[jj][k];
            float d = sqrtf(s);
            ld += __logf(d);
            float di = 1.f / d;
            dinv[jj] = di;
            L[jj][jj] = d;
#pragma unroll
            for (int i = jj + 1; i < NS_; ++i) {
                float t2 = L[i][jj];
#pragma unroll
                for (int k = 0; k < jj; ++k) t2 -= L[i][k] * L[jj][k];
                L[i][jj] = t2 * di;
            }
        }
        ld *= 2.f;

        float w[NS_];
#pragma unroll
        for (int i = 0; i < NS_; ++i) {
            float s = b[i];
#pragma unroll
            for (int k = 0; k < i; ++k) s -= L[i][k] * w[k];
            w[i] = s * dinv[i];
        }
        float mpost[NS_];
#pragma unroll
        for (int ii = NS_ - 1; ii >= 0; --ii) {
            float s = w[ii];
#pragma unroll
            for (int k = ii + 1; k < NS_; ++k) s -= L[k][ii] * mpost[k];
            mpost[ii] = s * dinv[ii];
        }

        float diff[NS_];
#pragma unroll
        for (int s = 0; s < NS_; ++s) diff[s] = xo[s] - mpost[s];
        float quad = 0.f;
#pragma unroll
        for (int jj = 0; jj < NS_; ++jj) {
            float u = 0.f;
#pragma unroll
            for (int i = jj; i < NS_; ++i) u += L[i][jj] * diff[i];
            quad += u * u;
        }

        contrib = 0.5f * (ld - quad) * (1.0f / (float)N_);
    }

#pragma unroll
    for (int off = 32; off; off >>= 1) contrib += __shfl_down(contrib, off);
    const int wid = threadIdx.x >> 6;
    if ((threadIdx.x & 63) == 0) wsum[wid] = contrib;
    __syncthreads();
    if (threadIdx.x == 0) {
        float s = 0.f;
#pragma unroll
        for (int i = 0; i < 4; ++i) s += wsum[i];
        atomicAdd(out, s);
    }
}

// ---------------------------------------------------------------------------
extern "C" void kernel_launch(void* const* d_in, const int* in_sizes, int n_in,
                              void* d_out, int out_size, void* d_ws, size_t ws_size,
                              hipStream_t stream)
{
    const float* Y      = (const float*)d_in[0];
    const float* X      = (const float*)d_in[1];
    const float* H      = (const float*)d_in[2];
    const float* C_w    = (const float*)d_in[4];
    const float* W_ih   = (const float*)d_in[5];
    const float* W_hh   = (const float*)d_in[6];
    const float* b_ih   = (const float*)d_in[7];
    const float* b_hh   = (const float*)d_in[8];
    const float* W_fc   = (const float*)d_in[9];
    const float* b_fc   = (const float*)d_in[10];
    const float* W_mean = (const float*)d_in[11];
    const float* b_mean = (const float*)d_in[12];
    const float* W_vars = (const float*)d_in[13];
    const float* b_vars = (const float*)d_in[14];
    float* out = (float*)d_out;

    float* h_out = (float*)d_ws;                       // 32.77 MB
    float* Ac = h_out + (size_t)N_ * T_ * HID_;
    float* Mc = Ac + NS_ * NO_;

    hipLaunchKernelGGL(setup_consts, dim3(1), dim3(64), 0, stream, H, C_w, Ac, Mc);
    hipLaunchKernelGGL(gru_kernel, dim3(N_), dim3(G3_), 0, stream,
                       Y, W_ih, W_hh, b_ih, b_hh, h_out);
    hipLaunchKernelGGL(init_out, dim3(1), dim3(1), 0, stream, out);
    hipLaunchKernelGGL(post_kernel, dim3((N_ * T_ + 255) / 256), dim3(256), 0, stream,
                       h_out, Y, X, W_fc, b_fc, W_mean, b_mean, W_vars, b_vars,
                       Ac, Mc, out);
}